// Round 10
// baseline (142.637 us; speedup 1.0000x reference)
//
#include <hip/hip_runtime.h>

#define N_NODES 40000
#define N_EDGES 640000
#define D 128
#define CAP 32            // bucket slots/node (u16) = 64 B = ONE cache line/node.
                          // Poisson(16): P(deg>32)~1e-4 -> ~10 overflow EDGES total,
                          // handled exactly via the side list below.
#define OVF_MAX 4096      // overflow list capacity (expected ~12 entries)
#define PREP_GRID 2560
#define XPITCH 136        // xs row pitch (floats); 544 B rows, 32B-aligned

typedef __attribute__((ext_vector_type(8))) short short8;
typedef __attribute__((ext_vector_type(4))) float float4v;

// round-to-nearest-even fp32 -> bf16 bits
static __device__ __forceinline__ unsigned bf16_rne(float f) {
    unsigned u = __float_as_uint(f);
    return (u + 0x7FFFu + ((u >> 16) & 1u)) >> 16;
}
static __device__ __forceinline__ unsigned pack2(float a, float b) {
    return bf16_rne(a) | (bf16_rne(b) << 16);
}

// ---------------------------------------------------------------------------
// K1: (a) edge hist + u16 bucket scatter (rank = hist atomic return). CAP=32
//     puts a node's whole row in ONE 64B line -> minimal partial-line RMW
//     flush traffic (the R7/R8-measured binder). Rare r>=CAP edges go to the
//     exact overflow side list. (b) fp32->bf16 feature pack; (c) W -> bf16
//     B-fragment order for the MFMA GEMM.
// ---------------------------------------------------------------------------
__global__ __launch_bounds__(256) void prep_kernel(
    const float* __restrict__ feat,
    const int*   __restrict__ src,
    const int*   __restrict__ dst,
    const float* __restrict__ W,
    unsigned*       __restrict__ featb,   // [N*D/2] packed 2xbf16
    unsigned*       __restrict__ wfrag,   // [8192] packed 2xbf16, frag order
    int*            __restrict__ deg,     // [N] zeroed by memset (true in-degree)
    unsigned short* __restrict__ bucket,  // [N*CAP] u16 src indices
    int*            __restrict__ ovf_cnt, // [1] zeroed by memset
    unsigned*       __restrict__ ovf)     // [OVF_MAX] (dst<<16)|src
{
    const int g  = blockIdx.x * 256 + threadIdx.x;
    const int GT = PREP_GRID * 256;

    for (int e = g; e < N_EDGES; e += GT) {
        int d = dst[e];
        int r = atomicAdd(&deg[d], 1);
        if (r < CAP) {
            bucket[(size_t)d * CAP + r] = (unsigned short)src[e];
        } else {
            int p = atomicAdd(ovf_cnt, 1);
            if (p < OVF_MAX) ovf[p] = ((unsigned)d << 16) | (unsigned)src[e];
        }
    }

    for (int i = g; i < N_NODES * D / 4; i += GT) {
        float4 f = reinterpret_cast<const float4*>(feat)[i];
        uint2 p;
        p.x = pack2(f.x, f.y);
        p.y = pack2(f.z, f.w);
        reinterpret_cast<uint2*>(featb)[i] = p;
    }

    if (g < 32 * 64) {          // 8 ntiles x 4 ktiles x 64 lanes
        const int tile = g >> 6, lane = g & 63;
        const int nt = tile >> 2, kt = tile & 3;
        const int n = nt * 16 + (lane & 15);
        const int k = kt * 32 + (lane >> 4) * 8;
        const float* wp = W + (size_t)n * D + k;
        uint4 p;
        p.x = pack2(wp[0], wp[1]);
        p.y = pack2(wp[2], wp[3]);
        p.z = pack2(wp[4], wp[5]);
        p.w = pack2(wp[6], wp[7]);
        reinterpret_cast<uint4*>(wfrag)[g] = p;
    }
}

// ---------------------------------------------------------------------------
// K2: fused aggregate + MFMA linear. Block = 512 thr = 8 waves = 16 nodes.
//     Wave owns nodes {2w, 2w+1}; bucket row (32 u16 = 1 line) preloaded in
//     one coalesced read; edge indices via __shfl; the two nodes' gather
//     loops INTERLEAVED (16 gathers in flight). Overflow side list folded in
//     exactly. sum featb[src] * feat[n]/deg (factorized u_mul_v) -> LDS xs.
//     GEMM: wave w computes ntile w via 4x mfma_f32_16x16x32_bf16.
// ---------------------------------------------------------------------------
__global__ __launch_bounds__(512) void agg_gemm(
    const float*          __restrict__ feat,
    const unsigned*       __restrict__ featb,
    const unsigned*       __restrict__ wfrag,
    const int*            __restrict__ deg,
    const unsigned short* __restrict__ bucket,
    const int*            __restrict__ ovf_cnt,
    const unsigned*       __restrict__ ovf,
    const float*          __restrict__ bias,
    float*                __restrict__ out)
{
    __shared__ float xs[16 * XPITCH];   // 8704 B
    const int t     = threadIdx.x;
    const int wave  = t >> 6;           // 0..7
    const int lane  = t & 63;
    const int node0 = blockIdx.x * 16;

    const int n0   = node0 + wave * 2;
    const int dgt0 = deg[n0];               // true degrees (for the mean)
    const int dgt1 = deg[n0 + 1];
    const int dg0  = min(dgt0, CAP);        // bucketed portion
    const int dg1  = min(dgt1, CAP);
    // whole bucket row (64 B) in registers; lanes 16+ duplicate the line
    const unsigned iw0 = reinterpret_cast<const unsigned*>(bucket + (size_t)n0 * CAP)[lane & 15];
    const unsigned iw1 = reinterpret_cast<const unsigned*>(bucket + (size_t)(n0 + 1) * CAP)[lane & 15];

    float2 acc0 = make_float2(0.f, 0.f);
    float2 acc1 = make_float2(0.f, 0.f);

    #define IDX0(i) ({ int w_ = __shfl((int)iw0, (i) >> 1, 64); ((i) & 1) ? ((w_ >> 16) & 0xFFFF) : (w_ & 0xFFFF); })
    #define IDX1(i) ({ int w_ = __shfl((int)iw1, (i) >> 1, 64); ((i) & 1) ? ((w_ >> 16) & 0xFFFF) : (w_ & 0xFFFF); })

    int i0 = 0, i1 = 0;
    while (i0 + 8 <= dg0 && i1 + 8 <= dg1) {   // 16 gathers in flight
        unsigned va[8], vb[8];
        #pragma unroll
        for (int j = 0; j < 8; ++j) va[j] = featb[((size_t)IDX0(i0 + j) << 6) + lane];
        #pragma unroll
        for (int j = 0; j < 8; ++j) vb[j] = featb[((size_t)IDX1(i1 + j) << 6) + lane];
        #pragma unroll
        for (int j = 0; j < 8; ++j) {
            acc0.x += __uint_as_float(va[j] << 16);
            acc0.y += __uint_as_float(va[j] & 0xFFFF0000u);
            acc1.x += __uint_as_float(vb[j] << 16);
            acc1.y += __uint_as_float(vb[j] & 0xFFFF0000u);
        }
        i0 += 8; i1 += 8;
    }
    for (; i0 + 8 <= dg0; i0 += 8) {
        unsigned va[8];
        #pragma unroll
        for (int j = 0; j < 8; ++j) va[j] = featb[((size_t)IDX0(i0 + j) << 6) + lane];
        #pragma unroll
        for (int j = 0; j < 8; ++j) {
            acc0.x += __uint_as_float(va[j] << 16);
            acc0.y += __uint_as_float(va[j] & 0xFFFF0000u);
        }
    }
    for (; i0 < dg0; ++i0) {
        unsigned v = featb[((size_t)IDX0(i0) << 6) + lane];
        acc0.x += __uint_as_float(v << 16);
        acc0.y += __uint_as_float(v & 0xFFFF0000u);
    }
    for (; i1 + 8 <= dg1; i1 += 8) {
        unsigned vb[8];
        #pragma unroll
        for (int j = 0; j < 8; ++j) vb[j] = featb[((size_t)IDX1(i1 + j) << 6) + lane];
        #pragma unroll
        for (int j = 0; j < 8; ++j) {
            acc1.x += __uint_as_float(vb[j] << 16);
            acc1.y += __uint_as_float(vb[j] & 0xFFFF0000u);
        }
    }
    for (; i1 < dg1; ++i1) {
        unsigned v = featb[((size_t)IDX1(i1) << 6) + lane];
        acc1.x += __uint_as_float(v << 16);
        acc1.y += __uint_as_float(v & 0xFFFF0000u);
    }
    #undef IDX0
    #undef IDX1

    // fold in overflow edges (expected ~12 entries globally; usually 0 hits)
    if (dgt0 > CAP || dgt1 > CAP) {
        const int no = min(*ovf_cnt, OVF_MAX);
        for (int j = 0; j < no; ++j) {
            unsigned w = ovf[j];
            int d_ = (int)(w >> 16);
            if (d_ == n0 || d_ == n0 + 1) {
                unsigned v = featb[((size_t)(w & 0xFFFF) << 6) + lane];
                float vx = __uint_as_float(v << 16);
                float vy = __uint_as_float(v & 0xFFFF0000u);
                if (d_ == n0) { acc0.x += vx; acc0.y += vy; }
                else          { acc1.x += vx; acc1.y += vy; }
            }
        }
    }

    {
        const float2 fd0 = reinterpret_cast<const float2*>(feat + (size_t)n0 * D)[lane];
        const float2 fd1 = reinterpret_cast<const float2*>(feat + (size_t)(n0 + 1) * D)[lane];
        const float inv0 = 1.0f / (float)max(dgt0, 1);
        const float inv1 = 1.0f / (float)max(dgt1, 1);
        xs[(wave * 2)     * XPITCH + lane * 2]     = acc0.x * fd0.x * inv0;
        xs[(wave * 2)     * XPITCH + lane * 2 + 1] = acc0.y * fd0.y * inv0;
        xs[(wave * 2 + 1) * XPITCH + lane * 2]     = acc1.x * fd1.x * inv1;
        xs[(wave * 2 + 1) * XPITCH + lane * 2 + 1] = acc1.y * fd1.y * inv1;
    }
    __syncthreads();

    // ---- MFMA GEMM: D[16 nodes][128 ch]; wave owns ntile = wave ----
    {
        const int arow = lane & 15;            // M index (node)
        const int aq   = lane >> 4;            // quad
        const int col  = lane & 15;            // N index within ntile

        short8 afrag[4];
        #pragma unroll
        for (int kt = 0; kt < 4; ++kt) {
            const float* xp = xs + arow * XPITCH + kt * 32 + aq * 8;
            union { short8 s; unsigned u[4]; } af;
            af.u[0] = pack2(xp[0], xp[1]);
            af.u[1] = pack2(xp[2], xp[3]);
            af.u[2] = pack2(xp[4], xp[5]);
            af.u[3] = pack2(xp[6], xp[7]);
            afrag[kt] = af.s;
        }

        float bo = bias[wave * 16 + col];
        float4v acc = (float4v){bo, bo, bo, bo};

        #pragma unroll
        for (int kt = 0; kt < 4; ++kt) {
            union { short8 s; uint4 u; } bf;
            bf.u = reinterpret_cast<const uint4*>(wfrag)[(wave * 4 + kt) * 64 + lane];
            acc = __builtin_amdgcn_mfma_f32_16x16x32_bf16(afrag[kt], bf.s, acc, 0, 0, 0);
        }

        // C/D layout: col = lane&15, row = (lane>>4)*4 + reg
        const int rbase = (lane >> 4) * 4;
        const int c = wave * 16 + col;
        #pragma unroll
        for (int r = 0; r < 4; ++r)
            out[(size_t)(node0 + rbase + r) * D + c] = acc[r];
    }
}

extern "C" void kernel_launch(void* const* d_in, const int* in_sizes, int n_in,
                              void* d_out, int out_size, void* d_ws, size_t ws_size,
                              hipStream_t stream)
{
    const float* feat = (const float*)d_in[0];
    const int*   src  = (const int*)  d_in[1];
    const int*   dst  = (const int*)  d_in[2];
    const float* W    = (const float*)d_in[3];
    const float* bias = (const float*)d_in[4];
    float* out = (float*)d_out;

    // Workspace (~13.2 MB), 16B-aligned segments:
    unsigned*       featb   = (unsigned*)d_ws;                         // [N*D/2]
    unsigned*       wfrag   = featb + (size_t)N_NODES * D / 2;         // [8192]
    unsigned short* bucket  = (unsigned short*)(wfrag + 8192);         // [N*CAP] u16
    int*            deg     = (int*)(bucket + (size_t)N_NODES * CAP);  // [N]
    int*            ovf_cnt = deg + N_NODES;                           // [1]
    unsigned*       ovf     = (unsigned*)(ovf_cnt + 1);                // [OVF_MAX]

    // zero deg + ovf_cnt in one memset (contiguous)
    hipMemsetAsync(deg, 0, (N_NODES + 1) * sizeof(int), stream);
    prep_kernel<<<PREP_GRID, 256, 0, stream>>>(feat, src, dst, W, featb, wfrag,
                                               deg, bucket, ovf_cnt, ovf);
    agg_gemm<<<N_NODES / 16, 512, 0, stream>>>(feat, featb, wfrag, deg, bucket,
                                               ovf_cnt, ovf, bias, out);
}

// Round 11
// 139.856 us; speedup vs baseline: 1.0199x; 1.0199x over previous
//
#include <hip/hip_runtime.h>

#define N_NODES 40000
#define N_EDGES 640000
#define D 128
#define CAP 64            // bucket slots/node (u16); in-deg ~ Poisson(16), P(>64) ~ 1e-13
#define PREP_GRID 1280    // half of R9: each thread owns TWO independent edge chains
#define XPITCH 136        // xs row pitch (floats); 544 B rows, 32B-aligned

typedef __attribute__((ext_vector_type(8))) short short8;
typedef __attribute__((ext_vector_type(4))) float float4v;

// round-to-nearest-even fp32 -> bf16 bits
static __device__ __forceinline__ unsigned bf16_rne(float f) {
    unsigned u = __float_as_uint(f);
    return (u + 0x7FFFu + ((u >> 16) & 1u)) >> 16;
}
static __device__ __forceinline__ unsigned pack2(float a, float b) {
    return bf16_rne(a) | (bf16_rne(b) << 16);
}

// ---------------------------------------------------------------------------
// K1: (a) edge hist + u16 bucket scatter. The edge phase is chain-latency
//     bound (R7: VALUBusy 2%, low BW) -> each thread now runs TWO independent
//     load->atomic->store chains back-to-back to double MLP on the binder.
//     (b) fp32->bf16 feature pack; (c) W -> bf16 B-fragment order.
// ---------------------------------------------------------------------------
__global__ __launch_bounds__(256) void prep_kernel(
    const float* __restrict__ feat,
    const int*   __restrict__ src,
    const int*   __restrict__ dst,
    const float* __restrict__ W,
    unsigned*       __restrict__ featb,   // [N*D/2] packed 2xbf16
    unsigned*       __restrict__ wfrag,   // [8192] packed 2xbf16, frag order
    int*            __restrict__ deg,     // [N] zeroed by memset
    unsigned short* __restrict__ bucket)  // [N*CAP] u16 src indices
{
    const int g  = blockIdx.x * 256 + threadIdx.x;
    const int GT = PREP_GRID * 256;       // 327680

    // ---- edge phase: two independent chains per thread ----
    {
        const int e0 = g;                 // < 327680 < N_EDGES always
        const int e1 = g + GT;
        const bool h1 = e1 < N_EDGES;
        int d0 = dst[e0];
        int s0 = src[e0];
        int d1 = h1 ? dst[e1] : 0;
        int s1 = h1 ? src[e1] : 0;
        int r0 = atomicAdd(&deg[d0], 1);              // both atomics in flight
        int r1 = h1 ? atomicAdd(&deg[d1], 1) : CAP;   // before either store
        if (r0 < CAP) bucket[(size_t)d0 * CAP + r0] = (unsigned short)s0;
        if (r1 < CAP) bucket[(size_t)d1 * CAP + r1] = (unsigned short)s1;
    }

    // ---- bf16 feature pack (streams under other waves' atomic stalls) ----
    for (int i = g; i < N_NODES * D / 4; i += GT) {
        float4 f = reinterpret_cast<const float4*>(feat)[i];
        uint2 p;
        p.x = pack2(f.x, f.y);
        p.y = pack2(f.z, f.w);
        reinterpret_cast<uint2*>(featb)[i] = p;
    }

    // ---- W -> B-fragment order (8 ntiles x 4 ktiles x 64 lanes) ----
    if (g < 32 * 64) {
        const int tile = g >> 6, lane = g & 63;
        const int nt = tile >> 2, kt = tile & 3;
        const int n = nt * 16 + (lane & 15);
        const int k = kt * 32 + (lane >> 4) * 8;
        const float* wp = W + (size_t)n * D + k;
        uint4 p;
        p.x = pack2(wp[0], wp[1]);
        p.y = pack2(wp[2], wp[3]);
        p.z = pack2(wp[4], wp[5]);
        p.w = pack2(wp[6], wp[7]);
        reinterpret_cast<uint4*>(wfrag)[g] = p;
    }
}

// ---------------------------------------------------------------------------
// K2 (= R9's best): fused aggregate + MFMA linear. Block = 512 thr = 8 waves
//     = 16 nodes. Wave owns nodes {2w, 2w+1}; bucket rows preloaded (one
//     coalesced read each), indices via __shfl; the two nodes' gather loops
//     INTERLEAVED (16 gathers in flight). sum featb[src] * feat[n]/deg
//     (factorized u_mul_v) -> LDS xs. GEMM: wave w computes ntile w via
//     4x mfma_f32_16x16x32_bf16.
// ---------------------------------------------------------------------------
__global__ __launch_bounds__(512) void agg_gemm(
    const float*          __restrict__ feat,
    const unsigned*       __restrict__ featb,
    const unsigned*       __restrict__ wfrag,
    const int*            __restrict__ deg,
    const unsigned short* __restrict__ bucket,
    const float*          __restrict__ bias,
    float*                __restrict__ out)
{
    __shared__ float xs[16 * XPITCH];   // 8704 B
    const int t     = threadIdx.x;
    const int wave  = t >> 6;           // 0..7
    const int lane  = t & 63;
    const int node0 = blockIdx.x * 16;

    const int n0  = node0 + wave * 2;
    const int dg0 = min(deg[n0],     CAP);
    const int dg1 = min(deg[n0 + 1], CAP);
    const unsigned iw0 = reinterpret_cast<const unsigned*>(bucket + (size_t)n0 * CAP)[lane & 31];
    const unsigned iw1 = reinterpret_cast<const unsigned*>(bucket + (size_t)(n0 + 1) * CAP)[lane & 31];

    float2 acc0 = make_float2(0.f, 0.f);
    float2 acc1 = make_float2(0.f, 0.f);

    #define IDX0(i) ({ int w_ = __shfl((int)iw0, (i) >> 1, 64); ((i) & 1) ? ((w_ >> 16) & 0xFFFF) : (w_ & 0xFFFF); })
    #define IDX1(i) ({ int w_ = __shfl((int)iw1, (i) >> 1, 64); ((i) & 1) ? ((w_ >> 16) & 0xFFFF) : (w_ & 0xFFFF); })

    int i0 = 0, i1 = 0;
    while (i0 + 8 <= dg0 && i1 + 8 <= dg1) {   // 16 gathers in flight
        unsigned va[8], vb[8];
        #pragma unroll
        for (int j = 0; j < 8; ++j) va[j] = featb[((size_t)IDX0(i0 + j) << 6) + lane];
        #pragma unroll
        for (int j = 0; j < 8; ++j) vb[j] = featb[((size_t)IDX1(i1 + j) << 6) + lane];
        #pragma unroll
        for (int j = 0; j < 8; ++j) {
            acc0.x += __uint_as_float(va[j] << 16);
            acc0.y += __uint_as_float(va[j] & 0xFFFF0000u);
            acc1.x += __uint_as_float(vb[j] << 16);
            acc1.y += __uint_as_float(vb[j] & 0xFFFF0000u);
        }
        i0 += 8; i1 += 8;
    }
    for (; i0 + 8 <= dg0; i0 += 8) {
        unsigned va[8];
        #pragma unroll
        for (int j = 0; j < 8; ++j) va[j] = featb[((size_t)IDX0(i0 + j) << 6) + lane];
        #pragma unroll
        for (int j = 0; j < 8; ++j) {
            acc0.x += __uint_as_float(va[j] << 16);
            acc0.y += __uint_as_float(va[j] & 0xFFFF0000u);
        }
    }
    for (; i0 < dg0; ++i0) {
        unsigned v = featb[((size_t)IDX0(i0) << 6) + lane];
        acc0.x += __uint_as_float(v << 16);
        acc0.y += __uint_as_float(v & 0xFFFF0000u);
    }
    for (; i1 + 8 <= dg1; i1 += 8) {
        unsigned vb[8];
        #pragma unroll
        for (int j = 0; j < 8; ++j) vb[j] = featb[((size_t)IDX1(i1 + j) << 6) + lane];
        #pragma unroll
        for (int j = 0; j < 8; ++j) {
            acc1.x += __uint_as_float(vb[j] << 16);
            acc1.y += __uint_as_float(vb[j] & 0xFFFF0000u);
        }
    }
    for (; i1 < dg1; ++i1) {
        unsigned v = featb[((size_t)IDX1(i1) << 6) + lane];
        acc1.x += __uint_as_float(v << 16);
        acc1.y += __uint_as_float(v & 0xFFFF0000u);
    }
    #undef IDX0
    #undef IDX1

    {
        const float2 fd0 = reinterpret_cast<const float2*>(feat + (size_t)n0 * D)[lane];
        const float2 fd1 = reinterpret_cast<const float2*>(feat + (size_t)(n0 + 1) * D)[lane];
        const float inv0 = 1.0f / (float)max(dg0, 1);
        const float inv1 = 1.0f / (float)max(dg1, 1);
        xs[(wave * 2)     * XPITCH + lane * 2]     = acc0.x * fd0.x * inv0;
        xs[(wave * 2)     * XPITCH + lane * 2 + 1] = acc0.y * fd0.y * inv0;
        xs[(wave * 2 + 1) * XPITCH + lane * 2]     = acc1.x * fd1.x * inv1;
        xs[(wave * 2 + 1) * XPITCH + lane * 2 + 1] = acc1.y * fd1.y * inv1;
    }
    __syncthreads();

    // ---- MFMA GEMM: D[16 nodes][128 ch]; wave owns ntile = wave ----
    {
        const int arow = lane & 15;            // M index (node)
        const int aq   = lane >> 4;            // quad
        const int col  = lane & 15;            // N index within ntile

        short8 afrag[4];
        #pragma unroll
        for (int kt = 0; kt < 4; ++kt) {
            const float* xp = xs + arow * XPITCH + kt * 32 + aq * 8;
            union { short8 s; unsigned u[4]; } af;
            af.u[0] = pack2(xp[0], xp[1]);
            af.u[1] = pack2(xp[2], xp[3]);
            af.u[2] = pack2(xp[4], xp[5]);
            af.u[3] = pack2(xp[6], xp[7]);
            afrag[kt] = af.s;
        }

        float bo = bias[wave * 16 + col];
        float4v acc = (float4v){bo, bo, bo, bo};

        #pragma unroll
        for (int kt = 0; kt < 4; ++kt) {
            union { short8 s; uint4 u; } bf;
            bf.u = reinterpret_cast<const uint4*>(wfrag)[(wave * 4 + kt) * 64 + lane];
            acc = __builtin_amdgcn_mfma_f32_16x16x32_bf16(afrag[kt], bf.s, acc, 0, 0, 0);
        }

        // C/D layout: col = lane&15, row = (lane>>4)*4 + reg
        const int rbase = (lane >> 4) * 4;
        const int c = wave * 16 + col;
        #pragma unroll
        for (int r = 0; r < 4; ++r)
            out[(size_t)(node0 + rbase + r) * D + c] = acc[r];
    }
}

extern "C" void kernel_launch(void* const* d_in, const int* in_sizes, int n_in,
                              void* d_out, int out_size, void* d_ws, size_t ws_size,
                              hipStream_t stream)
{
    const float* feat = (const float*)d_in[0];
    const int*   src  = (const int*)  d_in[1];
    const int*   dst  = (const int*)  d_in[2];
    const float* W    = (const float*)d_in[3];
    const float* bias = (const float*)d_in[4];
    float* out = (float*)d_out;

    // Workspace (~15.6 MB), 16B-aligned segments:
    unsigned*       featb  = (unsigned*)d_ws;                        // [N*D/2]
    unsigned*       wfrag  = featb + (size_t)N_NODES * D / 2;        // [8192]
    unsigned short* bucket = (unsigned short*)(wfrag + 8192);        // [N*CAP] u16
    int*            deg    = (int*)(bucket + (size_t)N_NODES * CAP); // [N]

    hipMemsetAsync(deg, 0, N_NODES * sizeof(int), stream);
    prep_kernel<<<PREP_GRID, 256, 0, stream>>>(feat, src, dst, W, featb, wfrag, deg, bucket);
    agg_gemm<<<N_NODES / 16, 512, 0, stream>>>(feat, featb, wfrag, deg, bucket, bias, out);
}